// Round 15
// baseline (163.234 us; speedup 1.0000x reference)
//
#include <hip/hip_runtime.h>
#include <hip/hip_bf16.h>

// out = conv9(in) @ M^T,  M = Wout @ Win
// R15: R12's two kernels merged into ONE via device-atomic grid barrier
// (all 512 blocks co-resident: 80KB LDS -> exactly 2/CU; launch_bounds caps
// VGPR at 256). Phase A: conv own panel rows (XCD-local U) + gemm_m spread.
// Phase B: R12's verified depth-2 gemm_out. ctr re-zeroed per launch by
// hipMemsetAsync; spin uses RMW atomics (plain loads can cache stale lines).

typedef unsigned short u16;
typedef unsigned int u32;
typedef unsigned long long u64;
typedef __attribute__((ext_vector_type(8))) short bf16x8;
typedef __attribute__((ext_vector_type(8))) unsigned short u16x8;
typedef __attribute__((ext_vector_type(4))) float f32x4;
typedef __attribute__((ext_vector_type(2))) u32 u32x2;

typedef __attribute__((address_space(1))) const void* as1_cvp;
typedef __attribute__((address_space(3))) void* as3_vp;

#define EDIM 512
#define NROW 16384

__device__ __forceinline__ u16 f2b(float x) {
  union { float f; u32 u; } c; c.f = x;
  return (u16)((c.u + 0x7fffu + ((c.u >> 16) & 1u)) >> 16);  // RNE
}
__device__ __forceinline__ u32 cvtpk(float lo, float hi) {
  u32 r;
  asm("v_cvt_pk_bf16_f32 %0, %1, %2" : "=v"(r) : "v"(lo), "v"(hi));
  return r;
}
__device__ __forceinline__ void async_cp16(const void* g, void* l) {
  __builtin_amdgcn_global_load_lds((as1_cvp)(u64)g, (as3_vp)(u32)(u64)l, 16, 0, 0);
}

// ---------------------------------------------------------------------------
// conv8: 8 out rows from a 16-row fp32 window (64 VGPR — no spill risk).
// ---------------------------------------------------------------------------
template <bool EDGE>
__device__ __forceinline__ void conv8(const float* __restrict__ in,
                                      u16* __restrict__ Uo, int rr0, int colv) {
  const float G[5] = {0.39894228040143270f, 0.24197072451914337f,
                      0.053990966513188063f, 0.0044318484119380075f,
                      1.3383022576488537e-4f};
  f32x4 w[16];
  if (EDGE) {
#pragma unroll
    for (int i = 0; i < 16; ++i) {
      int rr = rr0 - 4 + i;
      rr = rr < 0 ? 0 : (rr > NROW - 1 ? NROW - 1 : rr);
      w[i] = *(const f32x4*)(in + (u64)rr * EDIM + colv);
    }
  } else {
    const float* bp = in + (u64)(rr0 - 4) * EDIM + colv;
#pragma unroll
    for (int i = 0; i < 16; ++i) w[i] = *(const f32x4*)(bp + (u64)i * EDIM);
  }
#pragma unroll
  for (int j = 0; j < 8; ++j) {
    int rg = rr0 + j;
    f32x4 o = {};
#pragma unroll
    for (int k = 0; k < 9; ++k) {
      float g = G[k < 4 ? 4 - k : k - 4];
      if (EDGE) g = (((rg + k - 4) >> 12) == (rg >> 12)) ? g : 0.0f;
#pragma unroll
      for (int q = 0; q < 4; ++q) o[q] += g * w[j + k][q];
    }
    u32x2 p;
    p[0] = cvtpk(o[0], o[1]);
    p[1] = cvtpk(o[2], o[3]);
    *(u32x2*)(Uo + (u64)rg * EDIM + colv) = p;
  }
}

// ---------------------------------------------------------------------------
// gemm_m tile (proven body): M[f,e] = sum_c Wout[f,c]*Win[c,e], 64x64, BK=128.
// ---------------------------------------------------------------------------
__device__ __forceinline__ void gemm_m_tile(const float* __restrict__ Wout,
                                            const float* __restrict__ Win,
                                            u16* __restrict__ Mm,
                                            u16* lds, int bid, int t) {
  u16* la = lds;
  u16* lbt = lds + 8704;
  int w = t >> 6, l = t & 63, lr = l & 15, lk = l >> 4;
  int f0 = (bid >> 3) * 64, e0 = (bid & 7) * 64;
  int arow = t >> 2, acol = (t & 3) * 32;
  int cq = t >> 3, eo = (t & 7) * 8;
  const float* pA = Wout + (u64)(f0 + arow) * EDIM + acol;
  const float* pB = Win + (u64)(4 * cq) * EDIM + e0 + eo;
  f32x4 a8[8], b8[8];
#pragma unroll
  for (int i = 0; i < 8; ++i) a8[i] = *(const f32x4*)(pA + i * 4);
#pragma unroll
  for (int r = 0; r < 4; ++r) {
    b8[r * 2 + 0] = *(const f32x4*)(pB + r * EDIM);
    b8[r * 2 + 1] = *(const f32x4*)(pB + r * EDIM + 4);
  }
  f32x4 acc[4] = {};
  for (int kt = 0; kt < 4; ++kt) {
#pragma unroll
    for (int i = 0; i < 4; ++i) {
      u16x8 o;
#pragma unroll
      for (int q = 0; q < 4; ++q) { o[q] = f2b(a8[2 * i][q]); o[4 + q] = f2b(a8[2 * i + 1][q]); }
      *(u16x8*)(la + arow * 136 + acol + i * 8) = o;
    }
#pragma unroll
    for (int j = 0; j < 8; ++j) {
      u32x2 p;
      p[0] = cvtpk(b8[0 + (j >> 2)][j & 3], b8[2 + (j >> 2)][j & 3]);
      p[1] = cvtpk(b8[4 + (j >> 2)][j & 3], b8[6 + (j >> 2)][j & 3]);
      *(u32x2*)(lbt + (eo + j) * 136 + 4 * cq) = p;
    }
    asm volatile("s_waitcnt lgkmcnt(0)" ::: "memory");
    __builtin_amdgcn_sched_barrier(0);
    __builtin_amdgcn_s_barrier();
    if (kt < 3) {
      pA += 128; pB += (u64)128 * EDIM;
#pragma unroll
      for (int i = 0; i < 8; ++i) a8[i] = *(const f32x4*)(pA + i * 4);
#pragma unroll
      for (int r = 0; r < 4; ++r) {
        b8[r * 2 + 0] = *(const f32x4*)(pB + r * EDIM);
        b8[r * 2 + 1] = *(const f32x4*)(pB + r * EDIM + 4);
      }
    }
#pragma unroll
    for (int kk = 0; kk < 128; kk += 32) {
      bf16x8 a = *(const bf16x8*)(la + (w * 16 + lr) * 136 + kk + lk * 8);
#pragma unroll
      for (int ni = 0; ni < 4; ++ni) {
        bf16x8 bb = *(const bf16x8*)(lbt + (ni * 16 + lr) * 136 + kk + lk * 8);
        acc[ni] = __builtin_amdgcn_mfma_f32_16x16x32_bf16(a, bb, acc[ni], 0, 0, 0);
      }
    }
    asm volatile("s_waitcnt lgkmcnt(0)" ::: "memory");
    __builtin_amdgcn_sched_barrier(0);
    __builtin_amdgcn_s_barrier();
  }
#pragma unroll
  for (int ni = 0; ni < 4; ++ni)
#pragma unroll
    for (int r = 0; r < 4; ++r)
      Mm[(u64)(f0 + w * 16 + lk * 4 + r) * EDIM + e0 + ni * 16 + lr] = f2b(acc[ni][r]);
}

// ---------------------------------------------------------------------------
// Phase B macros (R12's verified depth-2 pipeline).
// ---------------------------------------------------------------------------
#define ISSA(KT, BUF)                                                          \
  _Pragma("unroll") for (int i = 0; i < 4; ++i)                                \
      async_cp16(gA + (KT) * 64 + (u64)i * 32 * EDIM,                          \
                 lds + (BUF) + t * 8 + i * 2048);
#define ISSB(KT, BUF)                                                          \
  _Pragma("unroll") for (int i = 0; i < 4; ++i)                                \
      async_cp16(gB + (KT) * 64 + (u64)i * 32 * EDIM,                          \
                 lds + 24576 + (BUF) + t * 8 + i * 2048);

#define GSTEP(KT, VM)                                                          \
  {                                                                            \
    asm volatile("s_waitcnt vmcnt(" #VM ")" ::: "memory");                     \
    __builtin_amdgcn_sched_barrier(0);                                         \
    __builtin_amdgcn_s_barrier();                                              \
    if ((KT) + 1 < 8) { ISSB((KT) + 1, (((KT) + 1) & 1) * 8192) }              \
    __builtin_amdgcn_sched_barrier(0);                                         \
    if ((KT) + 2 < 8) { ISSA((KT) + 2, (((KT) + 2) % 3) * 8192) }              \
    __builtin_amdgcn_sched_barrier(0);                                         \
    const int ab = ((KT) % 3) * 8192, bb = 24576 + ((KT) & 1) * 8192;          \
    _Pragma("unroll") for (int kk = 0; kk < 64; kk += 32) {                    \
      bf16x8 af[4], bv[4];                                                     \
      _Pragma("unroll") for (int mi = 0; mi < 4; ++mi)                         \
          af[mi] = *(const bf16x8*)(lds + ab + ard[mi] +                       \
                                    ((kk + lk * 8) ^ aswz[mi]));               \
      _Pragma("unroll") for (int ni = 0; ni < 4; ++ni)                         \
          bv[ni] = *(const bf16x8*)(lds + bb + brd[ni] +                       \
                                    ((kk + lk * 8) ^ bswz[ni]));               \
      _Pragma("unroll") for (int mi = 0; mi < 4; ++mi)                         \
        _Pragma("unroll") for (int ni = 0; ni < 4; ++ni)                       \
            acc[mi][ni] = __builtin_amdgcn_mfma_f32_16x16x32_bf16(             \
                af[mi], bv[ni], acc[mi][ni], 0, 0, 0);                         \
    }                                                                          \
  }

// ---------------------------------------------------------------------------
// mono: grid MUST be 512 x 256 (2 blocks/CU by 80KB LDS -> all co-resident).
// ---------------------------------------------------------------------------
__global__ __launch_bounds__(256, 2) void mono(const float* __restrict__ in,
                                               const float* __restrict__ Win,
                                               const float* __restrict__ Wout,
                                               u16* __restrict__ Mm,
                                               u16* __restrict__ Uo,
                                               float* __restrict__ out,
                                               u32* __restrict__ ctr) {
  __shared__ u16 lds[40960];  // 80 KB
  int t = threadIdx.x;
  int b = (int)blockIdx.x;
  int wg = (b & 7) * 64 + (b >> 3);  // bijective XCD swizzle (512 % 8 == 0)
  int m0 = (wg >> 2) * 128;
  int n0 = (wg & 3) * 128;

  // ---- Phase A1: conv this panel's own 32 rows -> XCD-local U
  {
    int r0 = m0 + (wg & 3) * 32;
    int colv = (t & 127) * 4;
    int rr0 = r0 + (t >> 7) * 16;
    bool edge = (((r0 - 4) >> 12) != ((r0 + 35) >> 12));
    if (edge) {
      conv8<true>(in, Uo, rr0, colv);
      conv8<true>(in, Uo, rr0 + 8, colv);
    } else {
      conv8<false>(in, Uo, rr0, colv);
      conv8<false>(in, Uo, rr0 + 8, colv);
    }
  }
  // ---- Phase A2: gemm_m on 64 blocks spread across XCDs (wg % 8 == 0)
  if ((wg & 7) == 0) gemm_m_tile(Wout, Win, Mm, lds, wg >> 3, t);

  // ---- device-scope grid barrier (RMW spin; ctr zeroed per launch by memset)
  __threadfence();
  __syncthreads();
  if (t == 0) {
    atomicAdd(ctr, 1u);
    while (atomicAdd(ctr, 0u) < 512u) __builtin_amdgcn_s_sleep(7);
  }
  __syncthreads();
  __threadfence();

  // ---- Phase B: gemm_out (R12 verified body)
  int l = t & 63, lr = l & 15, lk = l >> 4;
  int wv = t >> 6, wr = wv >> 1, wc = wv & 1;
  int soct = (t & 7) ^ ((t >> 3) & 7);
  const u16* gA = Uo + (u64)(m0 + (t >> 3)) * EDIM + soct * 8;
  const u16* gB = Mm + (u64)(n0 + (t >> 3)) * EDIM + soct * 8;

  int ard[4], aswz[4], brd[4], bswz[4];
#pragma unroll
  for (int mi = 0; mi < 4; ++mi) {
    int rA = wr * 64 + mi * 16 + lr;
    ard[mi] = rA * 64; aswz[mi] = (rA & 7) << 3;
  }
#pragma unroll
  for (int ni = 0; ni < 4; ++ni) {
    int rB = wc * 64 + ni * 16 + lr;
    brd[ni] = rB * 64; bswz[ni] = (rB & 7) << 3;
  }

  f32x4 acc[4][4] = {};

  ISSA(0, 0)
  ISSB(0, 0)
  __builtin_amdgcn_sched_barrier(0);
  ISSA(1, 8192)
  __builtin_amdgcn_sched_barrier(0);

  GSTEP(0, 4) GSTEP(1, 4) GSTEP(2, 4) GSTEP(3, 4)
  GSTEP(4, 4) GSTEP(5, 4) GSTEP(6, 4) GSTEP(7, 0)

#pragma unroll
  for (int mi = 0; mi < 4; ++mi)
#pragma unroll
    for (int ni = 0; ni < 4; ++ni)
#pragma unroll
      for (int rr = 0; rr < 4; ++rr)
        out[(u64)(m0 + wr * 64 + mi * 16 + lk * 4 + rr) * EDIM +
            n0 + wc * 64 + ni * 16 + lr] = acc[mi][ni][rr];
}

extern "C" void kernel_launch(void* const* d_in, const int* in_sizes, int n_in,
                              void* d_out, int out_size, void* d_ws, size_t ws_size,
                              hipStream_t stream) {
  const float* in   = (const float*)d_in[0];  // [4,4096,512] f32
  const float* Win  = (const float*)d_in[1];  // [512,512] f32
  const float* Wout = (const float*)d_in[2];  // [512,512] f32
  float* outp = (float*)d_out;                // [4,4096,512] f32

  u32* ctr = (u32*)d_ws;                                  // 4B counter @0
  u16* Mm  = (u16*)((char*)d_ws + 256);                   // 512KB
  u16* Uo  = (u16*)((char*)d_ws + 256 + 524288);          // 16.8MB

  hipMemsetAsync(d_ws, 0, 4, stream);  // re-arm barrier counter every launch
  hipLaunchKernelGGL(mono, dim3(512), dim3(256), 0, stream,
                     in, Win, Wout, Mm, Uo, outp, ctr);
}

// Round 16
// 35.810 us; speedup vs baseline: 4.5584x; 4.5584x over previous
//
#include <hip/hip_runtime.h>
#include <hip/hip_bf16.h>

// out = conv9(in) @ M^T,  M = Wout @ Win
// R16 = R12 with gemm_out at BK=32: LDS 40KB -> 4 blocks/CU (16 waves/CU, 2x
// latency hiding), 16 steps, depth-2 A prefetch (A triple, B double, vmcnt(2)).

typedef unsigned short u16;
typedef unsigned int u32;
typedef unsigned long long u64;
typedef __attribute__((ext_vector_type(8))) short bf16x8;
typedef __attribute__((ext_vector_type(8))) unsigned short u16x8;
typedef __attribute__((ext_vector_type(4))) float f32x4;
typedef __attribute__((ext_vector_type(2))) u32 u32x2;

typedef __attribute__((address_space(1))) const void* as1_cvp;
typedef __attribute__((address_space(3))) void* as3_vp;

#define EDIM 512
#define NROW 16384
#define CROWS 24                 // conv rows per block (2 groups x 12)
#define NCONVB 683               // ceil(16384/24)

__device__ __forceinline__ u16 f2b(float x) {
  union { float f; u32 u; } c; c.f = x;
  return (u16)((c.u + 0x7fffu + ((c.u >> 16) & 1u)) >> 16);  // RNE
}
__device__ __forceinline__ u32 cvtpk(float lo, float hi) {
  u32 r;
  asm("v_cvt_pk_bf16_f32 %0, %1, %2" : "=v"(r) : "v"(lo), "v"(hi));
  return r;
}
__device__ __forceinline__ void async_cp16(const void* g, void* l) {
  __builtin_amdgcn_global_load_lds((as1_cvp)(u64)g, (as3_vp)(u32)(u64)l, 16, 0, 0);
}

// ---------------------------------------------------------------------------
// conv: single-pass register window (R12 verified). Thread: 4 cols x 12 rows.
// ---------------------------------------------------------------------------
template <bool EDGE>
__device__ __forceinline__ void conv_body(const float* __restrict__ in,
                                          u16* __restrict__ Uo, int cb, int t) {
  const float G[5] = {0.39894228040143270f, 0.24197072451914337f,
                      0.053990966513188063f, 0.0044318484119380075f,
                      1.3383022576488537e-4f};
  int colv = t & 127;
  int rgrp = t >> 7;
  int r0 = cb * CROWS + rgrp * 12;
  f32x4 w[20];
  if (EDGE) {
#pragma unroll
    for (int i = 0; i < 20; ++i) {
      int rr = r0 - 4 + i;
      rr = rr < 0 ? 0 : (rr > NROW - 1 ? NROW - 1 : rr);
      w[i] = *(const f32x4*)(in + (u64)rr * EDIM + colv * 4);
    }
  } else {
    const float* bp = in + (u64)(r0 - 4) * EDIM + colv * 4;
#pragma unroll
    for (int i = 0; i < 20; ++i) w[i] = *(const f32x4*)(bp + (u64)i * EDIM);
  }
#pragma unroll
  for (int j = 0; j < 12; ++j) {
    int rg = r0 + j;
    f32x4 o = {};
#pragma unroll
    for (int k = 0; k < 9; ++k) {
      float g = G[k < 4 ? 4 - k : k - 4];
      if (EDGE) g = (((rg + k - 4) >> 12) == (rg >> 12)) ? g : 0.0f;
#pragma unroll
      for (int q = 0; q < 4; ++q) o[q] += g * w[j + k][q];
    }
    if (!EDGE || rg < NROW) {
      u32x2 p;
      p[0] = cvtpk(o[0], o[1]);
      p[1] = cvtpk(o[2], o[3]);
      *(u32x2*)(Uo + (u64)rg * EDIM + colv * 4) = p;
    }
  }
}

// ---------------------------------------------------------------------------
// prep: blocks 0..63 gemm_m (M = Wout@Win); blocks 64.. conv -> Uo. (R12)
// ---------------------------------------------------------------------------
__global__ __launch_bounds__(256) void prep(const float* __restrict__ in,
                                            const float* __restrict__ Win,
                                            const float* __restrict__ Wout,
                                            u16* __restrict__ Mm,
                                            u16* __restrict__ Uo) {
  __shared__ u16 plds[17408];
  int bid = (int)blockIdx.x, t = threadIdx.x;
  if (bid >= 64) {
    int cb = bid - 64;
    int c0 = cb * CROWS;
    bool edge = (((c0 - 4) >> 12) != ((c0 + CROWS + 3) >> 12));
    if (edge)
      conv_body<true>(in, Uo, cb, t);
    else
      conv_body<false>(in, Uo, cb, t);
    return;
  }
  u16* la = plds;
  u16* lbt = plds + 8704;
  int w = t >> 6, l = t & 63, lr = l & 15, lk = l >> 4;
  int f0 = (bid >> 3) * 64, e0 = (bid & 7) * 64;
  int arow = t >> 2, acol = (t & 3) * 32;
  int cq = t >> 3, eo = (t & 7) * 8;
  const float* pA = Wout + (u64)(f0 + arow) * EDIM + acol;
  const float* pB = Win + (u64)(4 * cq) * EDIM + e0 + eo;
  f32x4 a8[8], b8[8];
#pragma unroll
  for (int i = 0; i < 8; ++i) a8[i] = *(const f32x4*)(pA + i * 4);
#pragma unroll
  for (int r = 0; r < 4; ++r) {
    b8[r * 2 + 0] = *(const f32x4*)(pB + r * EDIM);
    b8[r * 2 + 1] = *(const f32x4*)(pB + r * EDIM + 4);
  }
  f32x4 acc[4] = {};
  for (int kt = 0; kt < 4; ++kt) {
#pragma unroll
    for (int i = 0; i < 4; ++i) {
      u16x8 o;
#pragma unroll
      for (int q = 0; q < 4; ++q) { o[q] = f2b(a8[2 * i][q]); o[4 + q] = f2b(a8[2 * i + 1][q]); }
      *(u16x8*)(la + arow * 136 + acol + i * 8) = o;
    }
#pragma unroll
    for (int j = 0; j < 8; ++j) {
      u32x2 p;
      p[0] = cvtpk(b8[0 + (j >> 2)][j & 3], b8[2 + (j >> 2)][j & 3]);
      p[1] = cvtpk(b8[4 + (j >> 2)][j & 3], b8[6 + (j >> 2)][j & 3]);
      *(u32x2*)(lbt + (eo + j) * 136 + 4 * cq) = p;
    }
    asm volatile("s_waitcnt lgkmcnt(0)" ::: "memory");
    __builtin_amdgcn_sched_barrier(0);
    __builtin_amdgcn_s_barrier();
    if (kt < 3) {
      pA += 128; pB += (u64)128 * EDIM;
#pragma unroll
      for (int i = 0; i < 8; ++i) a8[i] = *(const f32x4*)(pA + i * 4);
#pragma unroll
      for (int r = 0; r < 4; ++r) {
        b8[r * 2 + 0] = *(const f32x4*)(pB + r * EDIM);
        b8[r * 2 + 1] = *(const f32x4*)(pB + r * EDIM + 4);
      }
    }
#pragma unroll
    for (int kk = 0; kk < 128; kk += 32) {
      bf16x8 a = *(const bf16x8*)(la + (w * 16 + lr) * 136 + kk + lk * 8);
#pragma unroll
      for (int ni = 0; ni < 4; ++ni) {
        bf16x8 bb = *(const bf16x8*)(lbt + (ni * 16 + lr) * 136 + kk + lk * 8);
        acc[ni] = __builtin_amdgcn_mfma_f32_16x16x32_bf16(a, bb, acc[ni], 0, 0, 0);
      }
    }
    asm volatile("s_waitcnt lgkmcnt(0)" ::: "memory");
    __builtin_amdgcn_sched_barrier(0);
    __builtin_amdgcn_s_barrier();
  }
#pragma unroll
  for (int ni = 0; ni < 4; ++ni)
#pragma unroll
    for (int r = 0; r < 4; ++r)
      Mm[(u64)(f0 + w * 16 + lk * 4 + r) * EDIM + e0 + ni * 16 + lr] = f2b(acc[ni][r]);
}

// ---------------------------------------------------------------------------
// gemm_out: out[16384,512] = U @ M^T. 128x128 tile, BK=32, 16 steps.
// LDS 40KB (A0/A1/A2 @0/4096/8192 u16, B0/B1 @12288/16384) -> 4 blocks/CU.
// Depth-2 A prefetch; steady-state queue at step top = {B(kt)2, A(kt+1)2}
// -> vmcnt(2). Swizzle: octet ^= row&3 (both sides); 4-way read conflict ok.
// ---------------------------------------------------------------------------
#define ISSA2(KT, BUF)                                                         \
  _Pragma("unroll") for (int i = 0; i < 2; ++i)                                \
      async_cp16(gA + (KT) * 32 + (u64)i * 64 * EDIM,                          \
                 lds + (BUF) + t * 8 + i * 2048);
#define ISSB2(KT, BUF)                                                         \
  _Pragma("unroll") for (int i = 0; i < 2; ++i)                                \
      async_cp16(gB + (KT) * 32 + (u64)i * 64 * EDIM,                          \
                 lds + 12288 + (BUF) + t * 8 + i * 2048);

#define GSTEP(KT, VM)                                                          \
  {                                                                            \
    asm volatile("s_waitcnt vmcnt(" #VM ")" ::: "memory");                     \
    __builtin_amdgcn_sched_barrier(0);                                         \
    __builtin_amdgcn_s_barrier();                                              \
    if ((KT) + 1 < 16) { ISSB2((KT) + 1, (((KT) + 1) & 1) * 4096) }            \
    __builtin_amdgcn_sched_barrier(0);                                         \
    if ((KT) + 2 < 16) { ISSA2((KT) + 2, (((KT) + 2) % 3) * 4096) }            \
    __builtin_amdgcn_sched_barrier(0);                                         \
    const int ab = ((KT) % 3) * 4096, bb = 12288 + ((KT) & 1) * 4096;          \
    bf16x8 af[4], bv[4];                                                       \
    _Pragma("unroll") for (int mi = 0; mi < 4; ++mi)                           \
        af[mi] = *(const bf16x8*)(lds + ab + ard[mi] +                         \
                                  ((lk * 8) ^ aswz[mi]));                      \
    _Pragma("unroll") for (int ni = 0; ni < 4; ++ni)                           \
        bv[ni] = *(const bf16x8*)(lds + bb + brd[ni] +                         \
                                  ((lk * 8) ^ bswz[ni]));                      \
    _Pragma("unroll") for (int mi = 0; mi < 4; ++mi)                           \
      _Pragma("unroll") for (int ni = 0; ni < 4; ++ni)                         \
          acc[mi][ni] = __builtin_amdgcn_mfma_f32_16x16x32_bf16(               \
              af[mi], bv[ni], acc[mi][ni], 0, 0, 0);                           \
  }

__global__ __launch_bounds__(256, 4) void gemm_out(const u16* __restrict__ U,
                                                   const u16* __restrict__ Mm,
                                                   float* __restrict__ out) {
  __shared__ u16 lds[20480];  // 40 KB
  int t = threadIdx.x;
  int l = t & 63, lr = l & 15, lk = l >> 4;
  int wv = t >> 6, wr = wv >> 1, wc = wv & 1;
  int b = (int)blockIdx.x;
  int wg = (b & 7) * 64 + (b >> 3);  // bijective XCD swizzle (512 % 8 == 0)
  int m0 = (wg >> 2) * 128;
  int n0 = (wg & 3) * 128;

  // staging: thread covers rows (t>>2) and (t>>2)+64; source octet pre-swz
  int soct = (t & 3) ^ ((t >> 2) & 3);
  const u16* gA = U + (u64)(m0 + (t >> 2)) * EDIM + soct * 8;
  const u16* gB = Mm + (u64)(n0 + (t >> 2)) * EDIM + soct * 8;

  int ard[4], aswz[4], brd[4], bswz[4];
#pragma unroll
  for (int mi = 0; mi < 4; ++mi) {
    int rA = wr * 64 + mi * 16 + lr;
    ard[mi] = rA * 32; aswz[mi] = (rA & 3) << 3;
  }
#pragma unroll
  for (int ni = 0; ni < 4; ++ni) {
    int rB = wc * 64 + ni * 16 + lr;
    brd[ni] = rB * 32; bswz[ni] = (rB & 3) << 3;
  }

  f32x4 acc[4][4] = {};

  // prologue: A(0)->buf0, B(0)->B0, A(1)->buf1   (queue: A0:2, B0:2, A1:2)
  ISSA2(0, 0)
  ISSB2(0, 0)
  __builtin_amdgcn_sched_barrier(0);
  ISSA2(1, 4096)
  __builtin_amdgcn_sched_barrier(0);

  GSTEP(0, 2)  GSTEP(1, 2)  GSTEP(2, 2)  GSTEP(3, 2)
  GSTEP(4, 2)  GSTEP(5, 2)  GSTEP(6, 2)  GSTEP(7, 2)
  GSTEP(8, 2)  GSTEP(9, 2)  GSTEP(10, 2) GSTEP(11, 2)
  GSTEP(12, 2) GSTEP(13, 2) GSTEP(14, 2) GSTEP(15, 0)

  // epilogue: direct fp32 stores
#pragma unroll
  for (int mi = 0; mi < 4; ++mi)
#pragma unroll
    for (int ni = 0; ni < 4; ++ni)
#pragma unroll
      for (int rr = 0; rr < 4; ++rr)
        out[(u64)(m0 + wr * 64 + mi * 16 + lk * 4 + rr) * EDIM +
            n0 + wc * 64 + ni * 16 + lr] = acc[mi][ni][rr];
}

extern "C" void kernel_launch(void* const* d_in, const int* in_sizes, int n_in,
                              void* d_out, int out_size, void* d_ws, size_t ws_size,
                              hipStream_t stream) {
  const float* in   = (const float*)d_in[0];  // [4,4096,512] f32
  const float* Win  = (const float*)d_in[1];  // [512,512] f32
  const float* Wout = (const float*)d_in[2];  // [512,512] f32
  float* outp = (float*)d_out;                // [4,4096,512] f32

  u16* Mm = (u16*)d_ws;                       // 512*512 bf16
  u16* Uo = (u16*)d_ws + (u64)EDIM * EDIM;    // 16384*512 bf16

  hipLaunchKernelGGL(prep,     dim3(64 + NCONVB), dim3(256), 0, stream, in, Win, Wout, Mm, Uo);
  hipLaunchKernelGGL(gemm_out, dim3(512),         dim3(256), 0, stream, Uo, Mm, outp);
}